// Round 3
// baseline (308.868 us; speedup 1.0000x reference)
//
#include <hip/hip_runtime.h>
#include <cstdint>

typedef unsigned short ushort_t;
typedef __attribute__((ext_vector_type(8))) short v8s;
typedef __attribute__((ext_vector_type(4))) short v4s;
typedef __attribute__((ext_vector_type(4))) float v4f;

#define MFMA(a, b, c) __builtin_amdgcn_mfma_f32_16x16x32_bf16(a, b, c, 0, 0, 0)

__device__ __forceinline__ float bf2f(ushort_t u) {
    union { unsigned u; float f; } x; x.u = ((unsigned)u) << 16; return x.f;
}
__device__ __forceinline__ short f2bf(float f) {
    union { float f; unsigned u; } x; x.f = f;
    unsigned r = x.u + 0x7fffu + ((x.u >> 16) & 1u);   // RNE
    return (short)(r >> 16);
}

// ---------------- dtype detect: flag=1 if x is bf16-packed, 0 if fp32 ----------------
__global__ void detect_dtype(const unsigned* __restrict__ x, int* __restrict__ flag) {
    __shared__ int cnt;
    if (threadIdx.x == 0) cnt = 0;
    __syncthreads();
    unsigned w = x[threadIdx.x];
    int e = (w >> 7) & 0xFF;                     // exponent field of LOW half as bf16
    int hit = ((e >= 96 && e <= 135) || (w & 0xFFFFu) == 0) ? 1 : 0;
    atomicAdd(&cnt, hit);
    __syncthreads();
    if (threadIdx.x == 0) *flag = (cnt >= 160) ? 1 : 0;
}

// ---------------- convert x -> internal bf16 (8 elems/thread) ----------------
__global__ __launch_bounds__(256) void cvt_x(const void* __restrict__ xin,
                                             ushort_t* __restrict__ xb,
                                             const int* __restrict__ flagp, int n8) {
    int i = blockIdx.x * 256 + threadIdx.x;
    if (i >= n8) return;
    if (*flagp) {
        ((v8s*)xb)[i] = ((const v8s*)xin)[i];
    } else {
        const float* xf = (const float*)xin + (size_t)i * 8;
        v8s o;
        #pragma unroll
        for (int j = 0; j < 8; ++j) o[j] = f2bf(xf[j]);
        ((v8s*)xb)[i] = o;
    }
}

// ---------------- convert + transpose weights: out[c][r] = bf16(in[r][c]) ----------------
__global__ __launch_bounds__(256) void cvt_transpose(const void* __restrict__ in,
                                                     ushort_t* __restrict__ out,
                                                     const int* __restrict__ flagp,
                                                     int R, int C) {
    __shared__ ushort_t tile[32][33];
    int bx = blockIdx.x * 32, by = blockIdx.y * 32;
    int tx = threadIdx.x, ty = threadIdx.y;
    int isbf = *flagp;
    for (int i = ty; i < 32; i += 8) {
        size_t idx = (size_t)(by + i) * C + bx + tx;
        tile[i][tx] = isbf ? ((const ushort_t*)in)[idx]
                           : (ushort_t)f2bf(((const float*)in)[idx]);
    }
    __syncthreads();
    for (int i = ty; i < 32; i += 8) out[(size_t)(bx + i) * R + by + tx] = tile[tx][i];
}

// ---------------- GEMM: C[M][N] = A[M][K] * BT[N][K]^T, bf16 in ----------------
// OUTMODE 0: store bf16. OUTMODE 1: store fp32 if *flagp==0 else bf16.
template <int OUTMODE>
__global__ __launch_bounds__(256) void gemm_bt(const ushort_t* __restrict__ A,
                                               const ushort_t* __restrict__ BT,
                                               void* __restrict__ C,
                                               const int* __restrict__ flagp,
                                               int M, int N, int K) {
    __shared__ __align__(16) ushort_t As[128 * 32];
    __shared__ __align__(16) ushort_t Bs[128 * 32];
    int tid = threadIdx.x;
    int lane = tid & 63;
    int lr = lane & 15, lc = lane >> 4;
    int w = tid >> 6;
    int wr = (w >> 1) * 64, wc = (w & 1) * 64;
    int m0 = blockIdx.y * 128, n0 = blockIdx.x * 128;

    int c0 = tid, c1 = tid + 256;
    int r0 = c0 >> 2, s0 = c0 & 3;
    int r1 = c1 >> 2, s1 = c1 & 3;

    v4f acc[4][4] = {};

    for (int kt = 0; kt < K; kt += 32) {
        v8s a0 = *(const v8s*)(A + (size_t)(m0 + r0) * K + kt + s0 * 8);
        v8s a1 = *(const v8s*)(A + (size_t)(m0 + r1) * K + kt + s1 * 8);
        v8s b0 = *(const v8s*)(BT + (size_t)(n0 + r0) * K + kt + s0 * 8);
        v8s b1 = *(const v8s*)(BT + (size_t)(n0 + r1) * K + kt + s1 * 8);
        __syncthreads();
        *(v8s*)(As + (size_t)c0 * 8) = a0;
        *(v8s*)(As + (size_t)c1 * 8) = a1;
        *(v8s*)(Bs + (size_t)c0 * 8) = b0;
        *(v8s*)(Bs + (size_t)c1 * 8) = b1;
        __syncthreads();

        v8s af[4], bfr[4];
        #pragma unroll
        for (int i = 0; i < 4; ++i)
            af[i] = *(const v8s*)(As + (wr + i * 16 + lr) * 32 + lc * 8);
        #pragma unroll
        for (int j = 0; j < 4; ++j)
            bfr[j] = *(const v8s*)(Bs + (wc + j * 16 + lr) * 32 + lc * 8);
        #pragma unroll
        for (int i = 0; i < 4; ++i)
            #pragma unroll
            for (int j = 0; j < 4; ++j)
                acc[i][j] = MFMA(af[i], bfr[j], acc[i][j]);
    }
    int store_f32 = (OUTMODE == 1) && (*flagp == 0);
    #pragma unroll
    for (int i = 0; i < 4; ++i)
        #pragma unroll
        for (int j = 0; j < 4; ++j)
            #pragma unroll
            for (int r = 0; r < 4; ++r) {
                int row = m0 + wr + i * 16 + lc * 4 + r;
                int col = n0 + wc + j * 16 + lr;
                if (store_f32)
                    ((float*)C)[(size_t)row * N + col] = acc[i][j][r];
                else
                    ((ushort_t*)C)[(size_t)row * N + col] = (ushort_t)f2bf(acc[i][j][r]);
            }
}

// ---------------- RoPE + reshape ----------------
// qkv[4096][3072] bf16 -> Qr[bh][t][64] (rope, *0.125), Kr[bh][t][64] (rope), Vt[bh][64][t]
__global__ __launch_bounds__(256) void rope_reshape(const ushort_t* __restrict__ qkv,
                                                    ushort_t* __restrict__ Qr,
                                                    ushort_t* __restrict__ Kr,
                                                    ushort_t* __restrict__ Vt) {
    __shared__ __align__(16) ushort_t Vl[64][72];
    int tid = threadIdx.x;
    int tq = tid >> 2, dc = tid & 3;
    int t0 = blockIdx.x * 64;
    int bh = blockIdx.y;
    int b = bh >> 4, h = bh & 15;
    int t = t0 + tq;
    size_t rb = ((size_t)(b * 2048 + t)) * 3072 + h * 64;

    v8s qlo = *(const v8s*)(qkv + rb + dc * 8);
    v8s qhi = *(const v8s*)(qkv + rb + dc * 8 + 32);
    v8s klo = *(const v8s*)(qkv + rb + 1024 + dc * 8);
    v8s khi = *(const v8s*)(qkv + rb + 1024 + dc * 8 + 32);
    v8s vlo = *(const v8s*)(qkv + rb + 2048 + dc * 8);
    v8s vhi = *(const v8s*)(qkv + rb + 2048 + dc * 8 + 32);

    v8s qolo, qohi, kolo, kohi;
    #pragma unroll
    for (int j = 0; j < 8; ++j) {
        int d = dc * 8 + j;
        float inv_freq = __expf(-(float)d * 0.28782313662425575f);  // 10000^(-d/32)
        float ang = (float)t * inv_freq;
        float sn, cs;
        sincosf(ang, &sn, &cs);
        float cb = bf2f((ushort_t)f2bf(cs));   // match bf16 rope table if ref is bf16
        float sb = bf2f((ushort_t)f2bf(sn));
        float x1 = bf2f((ushort_t)qlo[j]), x2 = bf2f((ushort_t)qhi[j]);
        qolo[j] = f2bf((x1 * cb - x2 * sb) * 0.125f);
        qohi[j] = f2bf((x2 * cb + x1 * sb) * 0.125f);
        float k1 = bf2f((ushort_t)klo[j]), k2 = bf2f((ushort_t)khi[j]);
        kolo[j] = f2bf(k1 * cb - k2 * sb);
        kohi[j] = f2bf(k2 * cb + k1 * sb);
    }
    size_t ob = ((size_t)bh * 2048 + t) * 64;
    *(v8s*)(Qr + ob + dc * 8) = qolo;
    *(v8s*)(Qr + ob + dc * 8 + 32) = qohi;
    *(v8s*)(Kr + ob + dc * 8) = kolo;
    *(v8s*)(Kr + ob + dc * 8 + 32) = kohi;

    *(v8s*)(&Vl[tq][dc * 8]) = vlo;
    *(v8s*)(&Vl[tq][dc * 8 + 32]) = vhi;
    __syncthreads();
    int d = tid >> 2, tc = tid & 3;
    v8s o1, o2;
    #pragma unroll
    for (int k = 0; k < 8; ++k) o1[k] = (short)Vl[tc * 16 + k][d];
    #pragma unroll
    for (int k = 0; k < 8; ++k) o2[k] = (short)Vl[tc * 16 + 8 + k][d];
    size_t ob2 = ((size_t)bh * 64 + d) * 2048 + t0 + tc * 16;
    *(v8s*)(Vt + ob2) = o1;
    *(v8s*)(Vt + ob2 + 8) = o2;
}

// ---------------- flash attention, 1 wave/block, 64 q-rows ----------------
__global__ __launch_bounds__(64) void attn(const ushort_t* __restrict__ Qr,
                                           const ushort_t* __restrict__ Kr,
                                           const ushort_t* __restrict__ Vt,
                                           ushort_t* __restrict__ AO) {
    __shared__ __align__(16) ushort_t P[64 * 40];
    int lane = threadIdx.x;
    int lr = lane & 15, lc = lane >> 4;
    int q0 = blockIdx.x * 64;
    int bh = blockIdx.y;
    int b = bh >> 4, h = bh & 15;
    const ushort_t* Qb = Qr + ((size_t)bh * 2048 + q0) * 64;
    const ushort_t* Kb = Kr + (size_t)bh * 2048 * 64;
    const ushort_t* Vb = Vt + (size_t)bh * 64 * 2048;

    v8s qf[4][2];
    #pragma unroll
    for (int jq = 0; jq < 4; ++jq)
        #pragma unroll
        for (int kk = 0; kk < 2; ++kk)
            qf[jq][kk] = *(const v8s*)(Qb + (size_t)(jq * 16 + lr) * 64 + kk * 32 + lc * 8);

    v4f o[4][4] = {};
    float mi[4], li[4];
    #pragma unroll
    for (int jq = 0; jq < 4; ++jq) { mi[jq] = -1e30f; li[jq] = 0.f; }

    for (int sc = 0; sc < 2048; sc += 32) {
        v8s kf[2][2];
        #pragma unroll
        for (int hh = 0; hh < 2; ++hh)
            #pragma unroll
            for (int kk = 0; kk < 2; ++kk)
                kf[hh][kk] = *(const v8s*)(Kb + (size_t)(sc + hh * 16 + lr) * 64 + kk * 32 + lc * 8);

        v4f St[2][4] = {};
        #pragma unroll
        for (int hh = 0; hh < 2; ++hh)
            #pragma unroll
            for (int jq = 0; jq < 4; ++jq) {
                St[hh][jq] = MFMA(kf[hh][0], qf[jq][0], St[hh][jq]);
                St[hh][jq] = MFMA(kf[hh][1], qf[jq][1], St[hh][jq]);
            }

        v8s vf[4];
        #pragma unroll
        for (int i = 0; i < 4; ++i)
            vf[i] = *(const v8s*)(Vb + (size_t)(i * 16 + lr) * 2048 + sc + lc * 8);

        #pragma unroll
        for (int jq = 0; jq < 4; ++jq) {
            float cm = St[0][jq][0];
            #pragma unroll
            for (int hh = 0; hh < 2; ++hh)
                #pragma unroll
                for (int r = 0; r < 4; ++r) cm = fmaxf(cm, St[hh][jq][r]);
            cm = fmaxf(cm, __shfl_xor(cm, 16));
            cm = fmaxf(cm, __shfl_xor(cm, 32));
            float mnew = fmaxf(mi[jq], cm);
            float alpha = __expf(mi[jq] - mnew);
            mi[jq] = mnew;
            float rs = 0.f;
            #pragma unroll
            for (int hh = 0; hh < 2; ++hh)
                #pragma unroll
                for (int r = 0; r < 4; ++r) {
                    float ev = __expf(St[hh][jq][r] - mnew);
                    St[hh][jq][r] = ev;
                    rs += ev;
                }
            rs += __shfl_xor(rs, 16);
            rs += __shfl_xor(rs, 32);
            li[jq] = li[jq] * alpha + rs;
            #pragma unroll
            for (int i = 0; i < 4; ++i)
                #pragma unroll
                for (int r = 0; r < 4; ++r) o[i][jq][r] *= alpha;
            #pragma unroll
            for (int hh = 0; hh < 2; ++hh) {
                v4s pk;
                #pragma unroll
                for (int r = 0; r < 4; ++r) pk[r] = f2bf(St[hh][jq][r]);
                *(v4s*)(P + (jq * 16 + lr) * 40 + hh * 16 + lc * 4) = pk;
            }
        }
        __syncthreads();
        #pragma unroll
        for (int jq = 0; jq < 4; ++jq) {
            v8s pf = *(const v8s*)(P + (jq * 16 + lr) * 40 + lc * 8);
            #pragma unroll
            for (int i = 0; i < 4; ++i)
                o[i][jq] = MFMA(vf[i], pf, o[i][jq]);
        }
        __syncthreads();
    }
    #pragma unroll
    for (int jq = 0; jq < 4; ++jq) {
        float inv = 1.0f / li[jq];
        int t = q0 + jq * 16 + lr;
        #pragma unroll
        for (int i = 0; i < 4; ++i) {
            v4s pk;
            #pragma unroll
            for (int r = 0; r < 4; ++r) pk[r] = f2bf(o[i][jq][r] * inv);
            *(v4s*)(AO + (size_t)(b * 2048 + t) * 1024 + h * 64 + i * 16 + lc * 4) = pk;
        }
    }
}

extern "C" void kernel_launch(void* const* d_in, const int* in_sizes, int n_in,
                              void* d_out, int out_size, void* d_ws, size_t ws_size,
                              hipStream_t stream) {
    char* ws = (char*)d_ws;
    int*      flag  = (int*)ws;                         // [0,256)
    ushort_t* wqkvT = (ushort_t*)(ws + 256);            // bf16 [3072][1024], 6 MB
    ushort_t* woT   = (ushort_t*)(ws + 6291712);        // bf16 [1024][1024], 2 MB
    ushort_t* xb    = (ushort_t*)(ws + 8388864);        // bf16 [4096][1024], 8 MB (dead after gemm1)
    ushort_t* qkv   = (ushort_t*)(ws + 16777472);       // bf16 [4096][3072], 24 MB (dead after rope)
    ushort_t* Qr    = (ushort_t*)(ws + 41943296);       // 8 MB
    ushort_t* Vt    = (ushort_t*)(ws + 50331904);       // 8 MB
    ushort_t* Kr    = xb;                               // reuse xb region
    ushort_t* AO    = qkv;                              // reuse qkv region
    // peak ws use: 58720512 B (~56 MB)

    detect_dtype<<<1, 256, 0, stream>>>((const unsigned*)d_in[0], flag);
    cvt_x<<<2048, 256, 0, stream>>>(d_in[0], xb, flag, 524288);
    dim3 tb(32, 8);
    cvt_transpose<<<dim3(96, 32), tb, 0, stream>>>(d_in[1], wqkvT, flag, 1024, 3072);
    cvt_transpose<<<dim3(32, 32), tb, 0, stream>>>(d_in[2], woT, flag, 1024, 1024);
    gemm_bt<0><<<dim3(24, 32), 256, 0, stream>>>(xb, wqkvT, qkv, flag, 4096, 3072, 1024);
    rope_reshape<<<dim3(32, 32), 256, 0, stream>>>(qkv, Qr, Kr, Vt);
    attn<<<dim3(32, 32), 64, 0, stream>>>(Qr, Kr, Vt, AO);
    gemm_bt<1><<<dim3(8, 32), 256, 0, stream>>>(AO, woT, d_out, flag, 4096, 1024, 1024);
}

// Round 4
// 280.731 us; speedup vs baseline: 1.1002x; 1.1002x over previous
//
#include <hip/hip_runtime.h>
#include <cstdint>

typedef unsigned short ushort_t;
typedef __attribute__((ext_vector_type(8))) short v8s;
typedef __attribute__((ext_vector_type(4))) short v4s;
typedef __attribute__((ext_vector_type(2))) unsigned v2u;
typedef __attribute__((ext_vector_type(4))) float v4f;

#define MFMA(a, b, c) __builtin_amdgcn_mfma_f32_16x16x32_bf16(a, b, c, 0, 0, 0)

__device__ __forceinline__ float bf2f(ushort_t u) {
    union { unsigned u; float f; } x; x.u = ((unsigned)u) << 16; return x.f;
}
__device__ __forceinline__ short f2bf(float f) {
    union { float f; unsigned u; } x; x.f = f;
    unsigned r = x.u + 0x7fffu + ((x.u >> 16) & 1u);   // RNE
    return (short)(r >> 16);
}

// ---------------- dtype detect: flag=1 if x is bf16-packed, 0 if fp32 ----------------
__global__ void detect_dtype(const unsigned* __restrict__ x, int* __restrict__ flag) {
    __shared__ int cnt;
    if (threadIdx.x == 0) cnt = 0;
    __syncthreads();
    unsigned w = x[threadIdx.x];
    int e = (w >> 7) & 0xFF;
    int hit = ((e >= 96 && e <= 135) || (w & 0xFFFFu) == 0) ? 1 : 0;
    atomicAdd(&cnt, hit);
    __syncthreads();
    if (threadIdx.x == 0) *flag = (cnt >= 160) ? 1 : 0;
}

// ---------------- convert x -> internal bf16 (8 elems/thread) ----------------
__global__ __launch_bounds__(256) void cvt_x(const void* __restrict__ xin,
                                             ushort_t* __restrict__ xb,
                                             const int* __restrict__ flagp, int n8) {
    int i = blockIdx.x * 256 + threadIdx.x;
    if (i >= n8) return;
    if (*flagp) {
        ((v8s*)xb)[i] = ((const v8s*)xin)[i];
    } else {
        const float* xf = (const float*)xin + (size_t)i * 8;
        v8s o;
        #pragma unroll
        for (int j = 0; j < 8; ++j) o[j] = f2bf(xf[j]);
        ((v8s*)xb)[i] = o;
    }
}

// ---------------- convert + transpose weights: out[c][r] = bf16(in[r][c]) ----------------
__global__ __launch_bounds__(256) void cvt_transpose(const void* __restrict__ in,
                                                     ushort_t* __restrict__ out,
                                                     const int* __restrict__ flagp,
                                                     int R, int C) {
    __shared__ ushort_t tile[32][33];
    int bx = blockIdx.x * 32, by = blockIdx.y * 32;
    int tx = threadIdx.x, ty = threadIdx.y;
    int isbf = *flagp;
    for (int i = ty; i < 32; i += 8) {
        size_t idx = (size_t)(by + i) * C + bx + tx;
        tile[i][tx] = isbf ? ((const ushort_t*)in)[idx]
                           : (ushort_t)f2bf(((const float*)in)[idx]);
    }
    __syncthreads();
    for (int i = ty; i < 32; i += 8) out[(size_t)(bx + i) * R + by + tx] = tile[tx][i];
}

// ---------------- GEMM: C[M][N] = A[M][K] * BT[N][K]^T, bf16 in ----------------
template <int OUTMODE>
__global__ __launch_bounds__(256) void gemm_bt(const ushort_t* __restrict__ A,
                                               const ushort_t* __restrict__ BT,
                                               void* __restrict__ C,
                                               const int* __restrict__ flagp,
                                               int M, int N, int K) {
    __shared__ __align__(16) ushort_t As[128 * 32];
    __shared__ __align__(16) ushort_t Bs[128 * 32];
    int tid = threadIdx.x;
    int lane = tid & 63;
    int lr = lane & 15, lc = lane >> 4;
    int w = tid >> 6;
    int wr = (w >> 1) * 64, wc = (w & 1) * 64;
    int m0 = blockIdx.y * 128, n0 = blockIdx.x * 128;

    int c0 = tid, c1 = tid + 256;
    int r0 = c0 >> 2, s0 = c0 & 3;
    int r1 = c1 >> 2, s1 = c1 & 3;

    v4f acc[4][4] = {};

    for (int kt = 0; kt < K; kt += 32) {
        v8s a0 = *(const v8s*)(A + (size_t)(m0 + r0) * K + kt + s0 * 8);
        v8s a1 = *(const v8s*)(A + (size_t)(m0 + r1) * K + kt + s1 * 8);
        v8s b0 = *(const v8s*)(BT + (size_t)(n0 + r0) * K + kt + s0 * 8);
        v8s b1 = *(const v8s*)(BT + (size_t)(n0 + r1) * K + kt + s1 * 8);
        __syncthreads();
        *(v8s*)(As + (size_t)c0 * 8) = a0;
        *(v8s*)(As + (size_t)c1 * 8) = a1;
        *(v8s*)(Bs + (size_t)c0 * 8) = b0;
        *(v8s*)(Bs + (size_t)c1 * 8) = b1;
        __syncthreads();

        v8s af[4], bfr[4];
        #pragma unroll
        for (int i = 0; i < 4; ++i)
            af[i] = *(const v8s*)(As + (wr + i * 16 + lr) * 32 + lc * 8);
        #pragma unroll
        for (int j = 0; j < 4; ++j)
            bfr[j] = *(const v8s*)(Bs + (wc + j * 16 + lr) * 32 + lc * 8);
        #pragma unroll
        for (int i = 0; i < 4; ++i)
            #pragma unroll
            for (int j = 0; j < 4; ++j)
                acc[i][j] = MFMA(af[i], bfr[j], acc[i][j]);
    }
    int store_f32 = (OUTMODE == 1) && (*flagp == 0);
    #pragma unroll
    for (int i = 0; i < 4; ++i)
        #pragma unroll
        for (int j = 0; j < 4; ++j)
            #pragma unroll
            for (int r = 0; r < 4; ++r) {
                int row = m0 + wr + i * 16 + lc * 4 + r;
                int col = n0 + wc + j * 16 + lr;
                if (store_f32)
                    ((float*)C)[(size_t)row * N + col] = acc[i][j][r];
                else
                    ((ushort_t*)C)[(size_t)row * N + col] = (ushort_t)f2bf(acc[i][j][r]);
            }
}

// ---------------- RoPE + reshape ----------------
// Q scale folds 1/sqrt(64) AND log2(e) so attn can use raw v_exp_f32 (exp2).
#define QSCALE 0.18033688011112042f
__global__ __launch_bounds__(256) void rope_reshape(const ushort_t* __restrict__ qkv,
                                                    ushort_t* __restrict__ Qr,
                                                    ushort_t* __restrict__ Kr,
                                                    ushort_t* __restrict__ Vt) {
    __shared__ __align__(16) ushort_t Vl[64][72];
    int tid = threadIdx.x;
    int tq = tid >> 2, dc = tid & 3;
    int t0 = blockIdx.x * 64;
    int bh = blockIdx.y;
    int b = bh >> 4, h = bh & 15;
    int t = t0 + tq;
    size_t rb = ((size_t)(b * 2048 + t)) * 3072 + h * 64;

    v8s qlo = *(const v8s*)(qkv + rb + dc * 8);
    v8s qhi = *(const v8s*)(qkv + rb + dc * 8 + 32);
    v8s klo = *(const v8s*)(qkv + rb + 1024 + dc * 8);
    v8s khi = *(const v8s*)(qkv + rb + 1024 + dc * 8 + 32);
    v8s vlo = *(const v8s*)(qkv + rb + 2048 + dc * 8);
    v8s vhi = *(const v8s*)(qkv + rb + 2048 + dc * 8 + 32);

    v8s qolo, qohi, kolo, kohi;
    #pragma unroll
    for (int j = 0; j < 8; ++j) {
        int d = dc * 8 + j;
        float inv_freq = __expf(-(float)d * 0.28782313662425575f);  // 10000^(-d/32)
        float ang = (float)t * inv_freq;
        float sn, cs;
        sincosf(ang, &sn, &cs);
        float cb = bf2f((ushort_t)f2bf(cs));
        float sb = bf2f((ushort_t)f2bf(sn));
        float x1 = bf2f((ushort_t)qlo[j]), x2 = bf2f((ushort_t)qhi[j]);
        qolo[j] = f2bf((x1 * cb - x2 * sb) * QSCALE);
        qohi[j] = f2bf((x2 * cb + x1 * sb) * QSCALE);
        float k1 = bf2f((ushort_t)klo[j]), k2 = bf2f((ushort_t)khi[j]);
        kolo[j] = f2bf(k1 * cb - k2 * sb);
        kohi[j] = f2bf(k2 * cb + k1 * sb);
    }
    size_t ob = ((size_t)bh * 2048 + t) * 64;
    *(v8s*)(Qr + ob + dc * 8) = qolo;
    *(v8s*)(Qr + ob + dc * 8 + 32) = qohi;
    *(v8s*)(Kr + ob + dc * 8) = kolo;
    *(v8s*)(Kr + ob + dc * 8 + 32) = kohi;

    *(v8s*)(&Vl[tq][dc * 8]) = vlo;
    *(v8s*)(&Vl[tq][dc * 8 + 32]) = vhi;
    __syncthreads();
    int d = tid >> 2, tc = tid & 3;
    v8s o1, o2;
    #pragma unroll
    for (int k = 0; k < 8; ++k) o1[k] = (short)Vl[tc * 16 + k][d];
    #pragma unroll
    for (int k = 0; k < 8; ++k) o2[k] = (short)Vl[tc * 16 + 8 + k][d];
    size_t ob2 = ((size_t)bh * 64 + d) * 2048 + t0 + tc * 16;
    *(v8s*)(Vt + ob2) = o1;
    *(v8s*)(Vt + ob2 + 8) = o2;
}

// ---------------- flash attention, 4 waves/block, 32 q-rows/wave ----------------
// S^T = K*Q^T (softmax stats lane-local in q). exp2-space (scale folded in rope).
__global__ __launch_bounds__(256) void attn(const ushort_t* __restrict__ Qr,
                                            const ushort_t* __restrict__ Kr,
                                            const ushort_t* __restrict__ Vt,
                                            ushort_t* __restrict__ AO) {
    // per-wave 32x40 P tile, double-buffered by step parity: 4 waves * 2 * 1280 shorts
    __shared__ __align__(16) ushort_t P[4 * 2 * 1280];
    int tid = threadIdx.x;
    int lane = tid & 63;
    int W = tid >> 6;
    int lr = lane & 15, lc = lane >> 4;
    int q0 = blockIdx.x * 128 + W * 32;
    int bh = blockIdx.y;
    int b = bh >> 4, h = bh & 15;
    const ushort_t* Qb = Qr + ((size_t)bh * 2048 + q0) * 64;
    const ushort_t* Kb = Kr + (size_t)bh * 2048 * 64;
    const ushort_t* Vb = Vt + (size_t)bh * 64 * 2048;

    v8s qf[2][2];
    #pragma unroll
    for (int jq = 0; jq < 2; ++jq)
        #pragma unroll
        for (int kk = 0; kk < 2; ++kk)
            qf[jq][kk] = *(const v8s*)(Qb + (size_t)(jq * 16 + lr) * 64 + kk * 32 + lc * 8);

    v4f o[4][2] = {};
    float mi[2] = {-1e30f, -1e30f}, li[2] = {0.f, 0.f};

    for (int sc = 0; sc < 2048; sc += 32) {
        ushort_t* Pw = P + (W * 2 + ((sc >> 5) & 1)) * 1280;

        v8s kf[2][2];
        #pragma unroll
        for (int hh = 0; hh < 2; ++hh)
            #pragma unroll
            for (int kk = 0; kk < 2; ++kk)
                kf[hh][kk] = *(const v8s*)(Kb + (size_t)(sc + hh * 16 + lr) * 64 + kk * 32 + lc * 8);

        v4f St[2][2] = {};
        #pragma unroll
        for (int hh = 0; hh < 2; ++hh)
            #pragma unroll
            for (int jq = 0; jq < 2; ++jq) {
                St[hh][jq] = MFMA(kf[hh][0], qf[jq][0], St[hh][jq]);
                St[hh][jq] = MFMA(kf[hh][1], qf[jq][1], St[hh][jq]);
            }

        v8s vf[4];
        #pragma unroll
        for (int i = 0; i < 4; ++i)
            vf[i] = *(const v8s*)(Vb + (size_t)(i * 16 + lr) * 2048 + sc + lc * 8);

        // St lane layout: s-row = hh*16 + lc*4 + r, q-col = jq*16 + lr
        #pragma unroll
        for (int jq = 0; jq < 2; ++jq) {
            float cm = St[0][jq][0];
            #pragma unroll
            for (int hh = 0; hh < 2; ++hh)
                #pragma unroll
                for (int r = 0; r < 4; ++r) cm = fmaxf(cm, St[hh][jq][r]);
            cm = fmaxf(cm, __shfl_xor(cm, 16));
            cm = fmaxf(cm, __shfl_xor(cm, 32));
            bool grew = cm > mi[jq];
            float mnew = grew ? cm : mi[jq];
            float rs = 0.f;
            #pragma unroll
            for (int hh = 0; hh < 2; ++hh)
                #pragma unroll
                for (int r = 0; r < 4; ++r) {
                    float ev = __builtin_amdgcn_exp2f(St[hh][jq][r] - mnew);
                    St[hh][jq][r] = ev;
                    rs += ev;
                }
            rs += __shfl_xor(rs, 16);
            rs += __shfl_xor(rs, 32);
            if (__ballot(grew)) {   // wave-uniform: rescale only when some max grew
                float alpha = __builtin_amdgcn_exp2f(mi[jq] - mnew);
                mi[jq] = mnew;
                li[jq] = li[jq] * alpha + rs;
                #pragma unroll
                for (int i = 0; i < 4; ++i)
                    #pragma unroll
                    for (int r = 0; r < 4; ++r) o[i][jq][r] *= alpha;
            } else {
                li[jq] += rs;
            }
            // pack 8 probs -> 4 dwords (bf16 truncation via v_perm) and store 2x8B
            #pragma unroll
            for (int hh = 0; hh < 2; ++hh) {
                unsigned d0 = __builtin_amdgcn_perm(__float_as_uint(St[hh][jq][1]),
                                                    __float_as_uint(St[hh][jq][0]), 0x07060302u);
                unsigned d1 = __builtin_amdgcn_perm(__float_as_uint(St[hh][jq][3]),
                                                    __float_as_uint(St[hh][jq][2]), 0x07060302u);
                v2u pk = {d0, d1};
                *(v2u*)(Pw + (jq * 16 + lr) * 40 + hh * 16 + lc * 4) = pk;
            }
        }
        __syncthreads();   // P visible (double-buffered: no WAR barrier needed)
        #pragma unroll
        for (int jq = 0; jq < 2; ++jq) {
            v8s pf = *(const v8s*)(Pw + (jq * 16 + lr) * 40 + lc * 8);
            #pragma unroll
            for (int i = 0; i < 4; ++i)
                o[i][jq] = MFMA(vf[i], pf, o[i][jq]);
        }
    }
    // out lane layout: d = i*16 + lc*4 + r, q = jq*16 + lr
    #pragma unroll
    for (int jq = 0; jq < 2; ++jq) {
        float inv = 1.0f / li[jq];
        int t = q0 + jq * 16 + lr;
        #pragma unroll
        for (int i = 0; i < 4; ++i) {
            v4s pk;
            #pragma unroll
            for (int r = 0; r < 4; ++r) pk[r] = f2bf(o[i][jq][r] * inv);
            *(v4s*)(AO + (size_t)(b * 2048 + t) * 1024 + h * 64 + i * 16 + lc * 4) = pk;
        }
    }
}

extern "C" void kernel_launch(void* const* d_in, const int* in_sizes, int n_in,
                              void* d_out, int out_size, void* d_ws, size_t ws_size,
                              hipStream_t stream) {
    char* ws = (char*)d_ws;
    int*      flag  = (int*)ws;
    ushort_t* wqkvT = (ushort_t*)(ws + 256);
    ushort_t* woT   = (ushort_t*)(ws + 6291712);
    ushort_t* xb    = (ushort_t*)(ws + 8388864);
    ushort_t* qkv   = (ushort_t*)(ws + 16777472);
    ushort_t* Qr    = (ushort_t*)(ws + 41943296);
    ushort_t* Vt    = (ushort_t*)(ws + 50331904);
    ushort_t* Kr    = xb;     // reuse
    ushort_t* AO    = qkv;    // reuse

    detect_dtype<<<1, 256, 0, stream>>>((const unsigned*)d_in[0], flag);
    cvt_x<<<2048, 256, 0, stream>>>(d_in[0], xb, flag, 524288);
    dim3 tb(32, 8);
    cvt_transpose<<<dim3(96, 32), tb, 0, stream>>>(d_in[1], wqkvT, flag, 1024, 3072);
    cvt_transpose<<<dim3(32, 32), tb, 0, stream>>>(d_in[2], woT, flag, 1024, 1024);
    gemm_bt<0><<<dim3(24, 32), 256, 0, stream>>>(xb, wqkvT, qkv, flag, 4096, 3072, 1024);
    rope_reshape<<<dim3(32, 32), 256, 0, stream>>>(qkv, Qr, Kr, Vt);
    attn<<<dim3(16, 32), 256, 0, stream>>>(Qr, Kr, Vt, AO);
    gemm_bt<1><<<dim3(8, 32), 256, 0, stream>>>(AO, woT, d_out, flag, 4096, 1024, 1024);
}